// Round 3
// baseline (260.424 us; speedup 1.0000x reference)
//
#include <hip/hip_runtime.h>

#define B_SZ 128
#define IN_CAPS 1152
#define IN_DIM 8
#define N_CAPS 16
#define DIM 16

#define I_PER_BLK 4                  // one i per wave
#define ICN (IN_CAPS / I_PER_BLK)    // 288
#define BTN (B_SZ / 16)              // 8 (16 b per block)
#define OUT_ELEMS (B_SZ * N_CAPS * DIM)  // 32768

// Fused routing pass. Thread mapping: wave w (0..3) <-> i = ic*4 + w;
// lane = e_grp(2b)*16 + n(4b). Each thread holds W[n][i][4e][8d] = 32 floats
// (R2 lesson: 128-float per-thread W always spills; split e across lanes).
// logit: partial dot over own 4 e's + shfl_xor(16,32) over e_grps (in-wave).
// softmax over n: shfl_xor(1..8) (in-wave). i-sum: 4-wave LDS reduce, then
// fp32 atomicAdd into acc[b][n][e] (zeroed before pass).
template<bool ROUTED>
__global__ __launch_bounds__(256)
void caps_pass(const float* __restrict__ x, const float* __restrict__ W,
               const float* __restrict__ prev, float* __restrict__ acc)
{
    const int tid = threadIdx.x;
    const int w   = tid >> 6;          // wave = i_sub
    const int l   = tid & 63;
    const int eg  = l >> 4;            // e group: e = eg*4 + q
    const int n   = l & 15;
    const int ic  = blockIdx.x;        // 0..287
    const int bt  = blockIdx.y;        // 0..7
    const int i   = ic * I_PER_BLK + w;
    const int b0  = bt * 16;

    __shared__ float red[4][16][16];   // [i_sub][n][e]

    // W[n][i][eg*4+q][d] -> 32 VGPRs (4 rows x 8 floats), reused over 16 b's
    float Wreg[4][8];
    {
        const float4* wp = (const float4*)(W + (((size_t)n * IN_CAPS + i) * DIM + (eg << 2)) * IN_DIM);
        #pragma unroll
        for (int q = 0; q < 4; ++q) {
            float4 a = wp[2 * q], b4 = wp[2 * q + 1];
            Wreg[q][0] = a.x;  Wreg[q][1] = a.y;  Wreg[q][2] = a.z;  Wreg[q][3] = a.w;
            Wreg[q][4] = b4.x; Wreg[q][5] = b4.y; Wreg[q][6] = b4.z; Wreg[q][7] = b4.w;
        }
    }

    for (int bs = 0; bs < 16; ++bs) {
        const int b = b0 + bs;

        // x[b][i][0:8] — same 32B for all 64 lanes of this wave (L1 broadcast)
        const float4* xp = (const float4*)(x + ((size_t)b * IN_CAPS + i) * IN_DIM);
        float4 x0 = xp[0], x1 = xp[1];
        float xr[8] = {x0.x, x0.y, x0.z, x0.w, x1.x, x1.y, x1.z, x1.w};

        // hat[q] = sum_d x[b,i,d] * W[n,i,eg*4+q,d]   (32 FMA, all-register)
        float hat[4];
        #pragma unroll
        for (int q = 0; q < 4; ++q) {
            float h = 0.f;
            #pragma unroll
            for (int d = 0; d < 8; ++d) h = fmaf(xr[d], Wreg[q][d], h);
            hat[q] = h;
        }

        float c;
        if (ROUTED) {
            // logit = dot(prev[b,n,:], hat[b,n,i,:]); this thread's 4-e slice
            float4 o = ((const float4*)(prev + ((size_t)b << 8)))[(n << 2) + eg];
            float logit = fmaf(o.x, hat[0], fmaf(o.y, hat[1], fmaf(o.z, hat[2], o.w * hat[3])));
            logit += __shfl_xor(logit, 16);   // sum over e_grps
            logit += __shfl_xor(logit, 32);
            // softmax over n (16 contiguous lanes)
            float m = logit;
            #pragma unroll
            for (int msk = 8; msk >= 1; msk >>= 1)
                m = fmaxf(m, __shfl_xor(m, msk));
            float p = __expf(logit - m);
            float Z = p;
            #pragma unroll
            for (int msk = 8; msk >= 1; msk >>= 1)
                Z += __shfl_xor(Z, msk);
            c = p / Z;
        } else {
            c = 1.0f / 16.0f;   // softmax of all-zero logits
        }

        // stage c*hat (4 contiguous e's -> one b128 write, balanced 8-phase)
        float4 v = make_float4(c * hat[0], c * hat[1], c * hat[2], c * hat[3]);
        *(float4*)&red[w][n][eg << 2] = v;
        __syncthreads();
        {
            // thread tid -> (nn = tid>>4, ee = tid&15); conflict-free b32 reads
            const int nn = tid >> 4, ee = tid & 15;
            float s = red[0][nn][ee] + red[1][nn][ee] + red[2][nn][ee] + red[3][nn][ee];
            atomicAdd(acc + ((size_t)b << 8) + tid, s);
        }
        __syncthreads();
    }
}

// acc + B -> squash -> prevbuf/out; re-zero acc for the next pass's atomics.
// MODE 0: prevbuf = out0;  MODE 1: prevbuf += out1;  MODE 2: d_out = final.
template<int MODE>
__global__ __launch_bounds__(256)
void caps_squash(float* __restrict__ acc, const float* __restrict__ Bb,
                 float* __restrict__ prevbuf, float* __restrict__ out)
{
    const int g = blockIdx.x * 256 + threadIdx.x;   // g = b*256 + n*16 + e
    float t = acc[g] + Bb[g & 255];
    if (MODE < 2) acc[g] = 0.f;                     // ready for next pass

    float s2 = t * t;
    #pragma unroll
    for (int msk = 8; msk >= 1; msk >>= 1)
        s2 += __shfl_xor(s2, msk);
    float v = t * (sqrtf(s2) / (1.0f + s2));        // s2/(1+s2)/sqrt(s2) * t

    if (MODE == 0)      prevbuf[g] = v;
    else if (MODE == 1) prevbuf[g] = prevbuf[g] + v;
    else                out[g] = v;
}

extern "C" void kernel_launch(void* const* d_in, const int* in_sizes, int n_in,
                              void* d_out, int out_size, void* d_ws, size_t ws_size,
                              hipStream_t stream)
{
    const float* x  = (const float*)d_in[0];   // [128,1152,8]
    const float* W  = (const float*)d_in[1];   // [16,1152,16,8]
    const float* Bb = (const float*)d_in[2];   // [16,16]
    float* out = (float*)d_out;                // [128,16,16]

    float* prevbuf = (float*)d_ws;             // 32768 floats
    float* acc     = prevbuf + OUT_ELEMS;      // 32768 floats (atomic accumulator)

    hipMemsetAsync(acc, 0, OUT_ELEMS * sizeof(float), stream);

    dim3 pg(ICN, BTN);  // 288 x 8 = 2304 blocks

    // iter 0: c uniform (softmax of zeros)
    caps_pass<false><<<pg, 256, 0, stream>>>(x, W, nullptr, acc);
    caps_squash<0><<<OUT_ELEMS / 256, 256, 0, stream>>>(acc, Bb, prevbuf, nullptr);
    // iter 1: logits = dot(out0, hat)
    caps_pass<true><<<pg, 256, 0, stream>>>(x, W, prevbuf, acc);
    caps_squash<1><<<OUT_ELEMS / 256, 256, 0, stream>>>(acc, Bb, prevbuf, nullptr);
    // iter 2: logits = dot(out0+out1, hat)
    caps_pass<true><<<pg, 256, 0, stream>>>(x, W, prevbuf, acc);
    caps_squash<2><<<OUT_ELEMS / 256, 256, 0, stream>>>(acc, Bb, prevbuf, out);
}